// Round 3
// baseline (220.683 us; speedup 1.0000x reference)
//
#include <hip/hip_runtime.h>

typedef __bf16 bf16x8 __attribute__((ext_vector_type(8)));
typedef float f32x4 __attribute__((ext_vector_type(4)));
typedef unsigned short us4 __attribute__((ext_vector_type(4)));
typedef short s4 __attribute__((ext_vector_type(4)));

#define SCALE 0.17677669529663687f

__device__ __forceinline__ unsigned short f2bf(float f) {
    __bf16 h = (__bf16)f;                       // HW v_cvt (RNE)
    return __builtin_bit_cast(unsigned short, h);
}
__device__ __forceinline__ us4 pack4(float a, float b, float c, float d) {
    us4 r; r[0] = f2bf(a); r[1] = f2bf(b); r[2] = f2bf(c); r[3] = f2bf(d); return r;
}

// ---------------- prep: transpose+bf16 weights, build (bias[+mask]) table ----------------
__global__ void wa_prep(const float* __restrict__ qkv_w, const float* __restrict__ proj_w,
                        const float* __restrict__ rpbt, const float* __restrict__ mask,
                        unsigned short* __restrict__ wqkvt, unsigned short* __restrict__ wprojt,
                        float* __restrict__ tab, int use_bm) {
    int idx = blockIdx.x * 256 + threadIdx.x;
    if (idx < 49152) {                       // wqkvt[n][k] = qkv_w[k][n], bf16, (384,128)
        int n = idx >> 7, k = idx & 127;
        wqkvt[idx] = f2bf(qkv_w[k * 384 + n]);
    } else if (idx < 65536) {                // wprojt[n][k] = proj_w[k][n], bf16, (128,128)
        int j = idx - 49152;
        int n = j >> 7, k = j & 127;
        wprojt[j] = f2bf(proj_w[k * 128 + n]);
    } else {
        int j = idx - 65536;
        if (use_bm) {
            // BM[w][h][q][64] = bias + mask (k-stride 64)
            if (j < 64 * 4 * 49 * 64) {
                int k = j & 63; int t = j >> 6; int q = t % 49; t /= 49;
                int h = t & 3, w = t >> 2;
                float v = 0.f;
                if (k < 49) {
                    int rel = (q / 7 - k / 7 + 6) * 13 + (q % 7 - k % 7 + 6);
                    v = rpbt[rel * 4 + h] + mask[w * 2401 + q * 49 + k];
                }
                tab[j] = v;
            }
        } else {
            // biasP[h][q][64]
            if (j < 4 * 49 * 64) {
                int k = j & 63; int t = j >> 6; int q = t % 49; int h = t / 49;
                float v = 0.f;
                if (k < 49) {
                    int rel = (q / 7 - k / 7 + 6) * 13 + (q % 7 - k % 7 + 6);
                    v = rpbt[rel * 4 + h];
                }
                tab[j] = v;
            }
        }
    }
}

// ---------------- fused window attention: one block per window, 3 blocks/CU ----------------
// LDS map (50176 B total):
//   region0 (16384): Q [4][64][32] bf16, swz ((row&3)<<4)  -> later X [64][128] bf16, swz ((row&7)<<4)
//   region1 (33792): xb [64][128] bf16 swz ((row&7)<<4)    (phase 0/1)
//                    K  [4][64][32] swz ((row&3)<<4) + V [4][32][64] swz ((d&15)<<3)  (phase 1/2)
//                    outb [64][132] f32                    (phase 3 epilogue)
__global__ __launch_bounds__(512, 6) void wa_main(
    const float* __restrict__ x, const float* __restrict__ mask,
    const float* __restrict__ qkv_b, const float* __restrict__ proj_b,
    const unsigned short* __restrict__ wqkvt, const unsigned short* __restrict__ wprojt,
    const float* __restrict__ tab, int use_bm, float* __restrict__ out)
{
    __shared__ __align__(16) char smem[16384 + 33792];
    char* const reg0 = smem;
    char* const reg1 = smem + 16384;

    const int tid  = threadIdx.x;
    const int wv   = tid >> 6;
    const int lane = tid & 63;
    const int l15  = lane & 15;
    const int l4   = lane >> 4;
    const int b    = blockIdx.x;

    // ---- Phase 0: x (49x128 f32) -> xb bf16 (swizzled), zero-pad rows 49..63 ----
    {
        char* xb = reg1;
        const float* xp = x + (size_t)b * 6272;
        for (int i = tid; i < 1568; i += 512) {          // 49*128/4
            int row = i >> 5;
            int cb  = (i & 31) * 8;                      // byte offset in row
            f32x4 v = *reinterpret_cast<const f32x4*>(xp + i * 4);
            *reinterpret_cast<us4*>(xb + row * 256 + (cb ^ ((row & 7) << 4))) =
                pack4(v[0], v[1], v[2], v[3]);
        }
        us4 z = (us4)(unsigned short)0;
        for (int i = tid; i < 480; i += 512) {           // 15 rows * 32 chunks
            int row = 49 + (i >> 5);
            int cb  = (i & 31) * 8;
            *reinterpret_cast<us4*>(xb + row * 256 + (cb ^ ((row & 7) << 4))) = z;
        }
    }
    __syncthreads();

    // ---- Phase 1: qkv = x @ Wqkv + b (each wave: 48 cols); Q scaled by SCALE ----
    {
        const char* xb = reg1;
        f32x4 acc[3][4];
        for (int n = 0; n < 3; ++n)
            for (int m = 0; m < 4; ++m) acc[n][m] = (f32x4){0.f, 0.f, 0.f, 0.f};
        const int col0 = wv * 48 + l15;
        for (int kk = 0; kk < 4; ++kk) {
            bf16x8 a[4];
            for (int m = 0; m < 4; ++m) {
                int row = m * 16 + l15;
                a[m] = *reinterpret_cast<const bf16x8*>(
                    xb + row * 256 + ((kk * 64 + l4 * 16) ^ ((row & 7) << 4)));
            }
            for (int n = 0; n < 3; ++n) {
                bf16x8 bw = *reinterpret_cast<const bf16x8*>(wqkvt + (col0 + n * 16) * 128 + kk * 32 + l4 * 8);
                for (int m = 0; m < 4; ++m)
                    acc[n][m] = __builtin_amdgcn_mfma_f32_16x16x32_bf16(a[m], bw, acc[n][m], 0, 0, 0);
            }
        }
        __syncthreads();                                  // xb dead -> region1 reusable
        char* Ks = reg1;
        char* Vt = reg1 + 16384;
        for (int n = 0; n < 3; ++n) {
            int col = col0 + n * 16;
            int sec = col >> 7, c = col & 127, h = c >> 5, hc = c & 31;
            float bv = qkv_b[col];
            if (sec == 0) {
                float bq = bv * SCALE;
                for (int m = 0; m < 4; ++m)
                    for (int r = 0; r < 4; ++r) {
                        int row = m * 16 + l4 * 4 + r;
                        *reinterpret_cast<unsigned short*>(
                            reg0 + h * 4096 + row * 64 + ((hc * 2) ^ ((row & 3) << 4)))
                            = f2bf(acc[n][m][r] * SCALE + bq);
                    }
            } else if (sec == 1) {
                for (int m = 0; m < 4; ++m)
                    for (int r = 0; r < 4; ++r) {
                        int row = m * 16 + l4 * 4 + r;
                        *reinterpret_cast<unsigned short*>(
                            Ks + h * 4096 + row * 64 + ((hc * 2) ^ ((row & 3) << 4)))
                            = f2bf(acc[n][m][r] + bv);
                    }
            } else {
                for (int m = 0; m < 4; ++m) {
                    int tok0 = m * 16 + l4 * 4;           // token index (V transposed: [d][tok])
                    *reinterpret_cast<us4*>(
                        Vt + h * 4096 + hc * 128 + ((tok0 * 2) ^ ((hc & 15) << 3)))
                        = pack4(acc[n][m][0] + bv, acc[n][m][1] + bv,
                                acc[n][m][2] + bv, acc[n][m][3] + bv);
                }
            }
        }
    }
    __syncthreads();

    // ---- Phase 2: attention (swapped S^T = K·Q^T; softmax in-register; PV 16x16x16) ----
    {
        const int h = wv >> 1, half = wv & 1;
        const char* Ks = reg1;
        const char* Vt = reg1 + 16384;
        bf16x8 kf[4], qf[2];
        for (int n = 0; n < 4; ++n) {
            int row = n * 16 + l15;
            kf[n] = *reinterpret_cast<const bf16x8*>(
                Ks + h * 4096 + row * 64 + ((l4 * 16) ^ ((row & 3) << 4)));
        }
        for (int m = 0; m < 2; ++m) {
            int row = (half * 2 + m) * 16 + l15;
            qf[m] = *reinterpret_cast<const bf16x8*>(
                reg0 + h * 4096 + row * 64 + ((l4 * 16) ^ ((row & 3) << 4)));
        }
        f32x4 s[2][4];
        for (int m = 0; m < 2; ++m)
            for (int n = 0; n < 4; ++n) s[m][n] = (f32x4){0.f, 0.f, 0.f, 0.f};
        for (int m = 0; m < 2; ++m)
            for (int n = 0; n < 4; ++n)
                s[m][n] = __builtin_amdgcn_mfma_f32_16x16x32_bf16(kf[n], qf[m], s[m][n], 0, 0, 0);
        // lane (l15,l4) holds S[q = tile*16+l15][k = n*16 + l4*4 + r]

        const float* tp = tab + (size_t)(use_bm ? ((b & 63) * 4 + h) : h) * (49 * 64);
        const float* mp = mask + (size_t)(b & 63) * 2401;

        s4 pf[2][4];
        for (int m = 0; m < 2; ++m) {
            int tile = half * 2 + m;
            int qg = tile * 16 + l15;
            bool qok = (tile < 3) || (l15 == 0);
            int qc = qok ? qg : 48;
            const float* trow = tp + qc * 64 + l4 * 4;
            float vals[4][4];
            for (int n = 0; n < 4; ++n) {
                f32x4 t = *reinterpret_cast<const f32x4*>(trow + n * 16);
                for (int r = 0; r < 4; ++r) {
                    bool kok = (n < 3) || ((l4 | r) == 0);
                    float lv = -1e30f;
                    if (qok && kok) {
                        lv = s[m][n][r] + t[r];
                        if (!use_bm) lv += mp[qg * 49 + n * 16 + l4 * 4 + r];
                    }
                    vals[n][r] = lv;
                }
            }
            float mx = -1e30f;
            for (int n = 0; n < 4; ++n)
                for (int r = 0; r < 4; ++r) mx = fmaxf(mx, vals[n][r]);
            mx = fmaxf(mx, __shfl_xor(mx, 16));
            mx = fmaxf(mx, __shfl_xor(mx, 32));
            float p[4][4], sum = 0.f;
            for (int n = 0; n < 4; ++n)
                for (int r = 0; r < 4; ++r) { p[n][r] = __expf(vals[n][r] - mx); sum += p[n][r]; }
            sum += __shfl_xor(sum, 16);
            sum += __shfl_xor(sum, 32);
            float ri = __builtin_amdgcn_rcpf(sum);
            for (int n = 0; n < 4; ++n)
                pf[m][n] = __builtin_bit_cast(s4,
                    pack4(p[n][0] * ri, p[n][1] * ri, p[n][2] * ri, p[n][3] * ri));
        }
        // PV: X = P @ V via 16x16x16 (A = P in-register, B = V^T)
        f32x4 xacc[2][2];
        for (int m = 0; m < 2; ++m)
            for (int dt = 0; dt < 2; ++dt) xacc[m][dt] = (f32x4){0.f, 0.f, 0.f, 0.f};
        for (int n = 0; n < 4; ++n)
            for (int dt = 0; dt < 2; ++dt) {
                s4 vf = *reinterpret_cast<const s4*>(
                    Vt + h * 4096 + (dt * 16 + l15) * 128 + ((n * 32 + l4 * 8) ^ (l15 << 3)));
                for (int m = 0; m < 2; ++m)
                    xacc[m][dt] = __builtin_amdgcn_mfma_f32_16x16x16bf16_1k(pf[m][n], vf, xacc[m][dt], 0, 0, 0);
            }
        __syncthreads();           // all waves' qf loads done -> region0 becomes X
        for (int m = 0; m < 2; ++m)
            for (int dt = 0; dt < 2; ++dt)
                for (int r = 0; r < 4; ++r) {
                    int row = (half * 2 + m) * 16 + l4 * 4 + r;
                    int col = h * 32 + dt * 16 + l15;
                    *reinterpret_cast<unsigned short*>(
                        reg0 + row * 256 + ((col * 2) ^ ((row & 7) << 4))) = f2bf(xacc[m][dt][r]);
                }
    }
    __syncthreads();

    // ---- Phase 3: out = X @ Wproj + b; stage f32 in LDS, coalesced f32x4 store ----
    {
        const int col = wv * 16 + l15;
        f32x4 o[4];
        for (int m = 0; m < 4; ++m) o[m] = (f32x4){0.f, 0.f, 0.f, 0.f};
        for (int kk = 0; kk < 4; ++kk) {
            bf16x8 a[4];
            for (int m = 0; m < 4; ++m) {
                int row = m * 16 + l15;
                a[m] = *reinterpret_cast<const bf16x8*>(
                    reg0 + row * 256 + ((kk * 64 + l4 * 16) ^ ((row & 7) << 4)));
            }
            bf16x8 bw = *reinterpret_cast<const bf16x8*>(wprojt + col * 128 + kk * 32 + l4 * 8);
            for (int m = 0; m < 4; ++m)
                o[m] = __builtin_amdgcn_mfma_f32_16x16x32_bf16(a[m], bw, o[m], 0, 0, 0);
        }
        float pb = proj_b[col];
        float* outb = (float*)reg1;                       // [64][132]
        for (int m = 0; m < 4; ++m)
            for (int r = 0; r < 4; ++r) {
                int row = m * 16 + l4 * 4 + r;
                outb[row * 132 + col] = o[m][r] + pb;
            }
    }
    __syncthreads();
    {
        const float* outb = (const float*)reg1;
        float* op = out + (size_t)b * 6272;
        for (int i = tid; i < 1568; i += 512) {
            int row = i >> 5, c0 = (i & 31) << 2;
            f32x4 v; 
            v[0] = outb[row * 132 + c0 + 0];
            v[1] = outb[row * 132 + c0 + 1];
            v[2] = outb[row * 132 + c0 + 2];
            v[3] = outb[row * 132 + c0 + 3];
            *reinterpret_cast<f32x4*>(op + i * 4) = v;
        }
    }
}

extern "C" void kernel_launch(void* const* d_in, const int* in_sizes, int n_in,
                              void* d_out, int out_size, void* d_ws, size_t ws_size,
                              hipStream_t stream) {
    const float* x      = (const float*)d_in[0];
    const float* mask   = (const float*)d_in[1];
    const float* qkv_w  = (const float*)d_in[2];
    const float* qkv_b  = (const float*)d_in[3];
    const float* proj_w = (const float*)d_in[4];
    const float* proj_b = (const float*)d_in[5];
    const float* rpbt   = (const float*)d_in[6];
    float* out = (float*)d_out;

    unsigned short* wqkvt  = (unsigned short*)d_ws;                       // 98304 B
    unsigned short* wprojt = (unsigned short*)((char*)d_ws + 98304);      // 32768 B
    float*          tab    = (float*)((char*)d_ws + 131072);

    const size_t needed_big = 131072 + (size_t)64 * 4 * 49 * 64 * 4;      // ~3.34 MB
    int use_bm = (ws_size >= needed_big) ? 1 : 0;
    int total  = 65536 + (use_bm ? 64 * 4 * 49 * 64 : 4 * 49 * 64);

    wa_prep<<<(total + 255) / 256, 256, 0, stream>>>(qkv_w, proj_w, rpbt, mask, wqkvt, wprojt, tab, use_bm);
    wa_main<<<4096, 512, 0, stream>>>(x, mask, qkv_b, proj_b, wqkvt, wprojt, tab, use_bm, out);
}

// Round 4
// 189.627 us; speedup vs baseline: 1.1638x; 1.1638x over previous
//
#include <hip/hip_runtime.h>

typedef __bf16 bf16x8 __attribute__((ext_vector_type(8)));
typedef float f32x4 __attribute__((ext_vector_type(4)));
typedef unsigned short us4 __attribute__((ext_vector_type(4)));
typedef short s4 __attribute__((ext_vector_type(4)));

#define SCALE 0.17677669529663687f

__device__ __forceinline__ unsigned short f2bf(float f) {
    __bf16 h = (__bf16)f;                       // HW v_cvt (RNE)
    return __builtin_bit_cast(unsigned short, h);
}
__device__ __forceinline__ us4 pack4(float a, float b, float c, float d) {
    us4 r; r[0] = f2bf(a); r[1] = f2bf(b); r[2] = f2bf(c); r[3] = f2bf(d); return r;
}

// ---------------- prep: transpose+bf16 weights, build (bias[+mask]) table ----------------
__global__ void wa_prep(const float* __restrict__ qkv_w, const float* __restrict__ proj_w,
                        const float* __restrict__ rpbt, const float* __restrict__ mask,
                        unsigned short* __restrict__ wqkvt, unsigned short* __restrict__ wprojt,
                        float* __restrict__ tab, int use_bm) {
    int idx = blockIdx.x * 256 + threadIdx.x;
    if (idx < 49152) {                       // wqkvt[n][k] = qkv_w[k][n], bf16, (384,128)
        int n = idx >> 7, k = idx & 127;
        wqkvt[idx] = f2bf(qkv_w[k * 384 + n]);
    } else if (idx < 65536) {                // wprojt[n][k] = proj_w[k][n], bf16, (128,128)
        int j = idx - 49152;
        int n = j >> 7, k = j & 127;
        wprojt[j] = f2bf(proj_w[k * 128 + n]);
    } else {
        int j = idx - 65536;
        if (use_bm) {
            // BM[w][h][q][64] = bias + mask (k-stride 64)
            if (j < 64 * 4 * 49 * 64) {
                int k = j & 63; int t = j >> 6; int q = t % 49; t /= 49;
                int h = t & 3, w = t >> 2;
                float v = 0.f;
                if (k < 49) {
                    int rel = (q / 7 - k / 7 + 6) * 13 + (q % 7 - k % 7 + 6);
                    v = rpbt[rel * 4 + h] + mask[w * 2401 + q * 49 + k];
                }
                tab[j] = v;
            }
        } else {
            // biasP[h][q][64]
            if (j < 4 * 49 * 64) {
                int k = j & 63; int t = j >> 6; int q = t % 49; int h = t / 49;
                float v = 0.f;
                if (k < 49) {
                    int rel = (q / 7 - k / 7 + 6) * 13 + (q % 7 - k % 7 + 6);
                    v = rpbt[rel * 4 + h];
                }
                tab[j] = v;
            }
        }
    }
}

// ---------------- fused window attention: one block per window, 3 blocks/CU ----------------
// LDS (49152 B): reg0 (16384): Q [4][64][32] bf16 swz((row&3)<<4) -> X [64][128] swz((row&7)<<4)
//                reg1 (32768): xb [64][128] swz((row&7)<<4)
//                              -> K [4][64][32] swz((row&3)<<4) + V [4][32][64] swz((d&15)<<3)
//                              -> outb [64][128] f32 swz((row&7)<<4)
// Register discipline: peak live ~55-60 total (arch+acc) to fit the 84-reg cap at 6 waves/EU.
__global__ __launch_bounds__(512, 6) void wa_main(
    const float* __restrict__ x, const float* __restrict__ mask,
    const float* __restrict__ qkv_b, const float* __restrict__ proj_b,
    const unsigned short* __restrict__ wqkvt, const unsigned short* __restrict__ wprojt,
    const float* __restrict__ tab, int use_bm, float* __restrict__ out)
{
    __shared__ __align__(16) char smem[16384 + 32768];
    char* const reg0 = smem;
    char* const reg1 = smem + 16384;

    const int tid  = threadIdx.x;
    const int wv   = tid >> 6;
    const int lane = tid & 63;
    const int l15  = lane & 15;
    const int l4   = lane >> 4;
    const int b    = blockIdx.x;

    // ---- Phase 0: x (49x128 f32) -> xb bf16 (swizzled), zero-pad rows 49..63 ----
    {
        char* xb = reg1;
        const float* xp = x + (size_t)b * 6272;
        for (int i = tid; i < 1568; i += 512) {          // 49*128/4
            int row = i >> 5;
            int cb  = (i & 31) * 8;
            f32x4 v = *reinterpret_cast<const f32x4*>(xp + i * 4);
            *reinterpret_cast<us4*>(xb + row * 256 + (cb ^ ((row & 7) << 4))) =
                pack4(v[0], v[1], v[2], v[3]);
        }
        us4 z = (us4)(unsigned short)0;
        for (int i = tid; i < 480; i += 512) {           // 15 rows * 32 chunks
            int row = 49 + (i >> 5);
            int cb  = (i & 31) * 8;
            *reinterpret_cast<us4*>(xb + row * 256 + (cb ^ ((row & 7) << 4))) = z;
        }
    }
    __syncthreads();

    // ---- Phase 1: qkv. Wave wv owns 16-col tile wv of each of Q, K, V (sequential passes) ----
    {
        const char* xb = reg1;
        const int h  = wv >> 1;
        const int hc = (wv & 1) * 16 + l15;

        // pass Q
        {
            const int col = wv * 16 + l15;
            f32x4 acc[4];
            for (int m = 0; m < 4; ++m) acc[m] = (f32x4){0.f, 0.f, 0.f, 0.f};
            for (int kk = 0; kk < 4; ++kk) {
                bf16x8 bw = *reinterpret_cast<const bf16x8*>(wqkvt + col * 128 + kk * 32 + l4 * 8);
                for (int m = 0; m < 4; ++m) {
                    int row = m * 16 + l15;
                    bf16x8 a = *reinterpret_cast<const bf16x8*>(
                        xb + row * 256 + ((kk * 64 + l4 * 16) ^ ((row & 7) << 4)));
                    acc[m] = __builtin_amdgcn_mfma_f32_16x16x32_bf16(a, bw, acc[m], 0, 0, 0);
                }
            }
            float bq = qkv_b[col] * SCALE;
            for (int m = 0; m < 4; ++m)
                for (int r = 0; r < 4; ++r) {
                    int row = m * 16 + l4 * 4 + r;
                    *reinterpret_cast<unsigned short*>(
                        reg0 + h * 4096 + row * 64 + ((hc * 2) ^ ((row & 3) << 4)))
                        = f2bf(acc[m][r] * SCALE + bq);
                }
        }
        // pass K (hold), pass V (hold)
        f32x4 akk[4], avv[4];
        {
            const int col = 128 + wv * 16 + l15;
            for (int m = 0; m < 4; ++m) akk[m] = (f32x4){0.f, 0.f, 0.f, 0.f};
            for (int kk = 0; kk < 4; ++kk) {
                bf16x8 bw = *reinterpret_cast<const bf16x8*>(wqkvt + col * 128 + kk * 32 + l4 * 8);
                for (int m = 0; m < 4; ++m) {
                    int row = m * 16 + l15;
                    bf16x8 a = *reinterpret_cast<const bf16x8*>(
                        xb + row * 256 + ((kk * 64 + l4 * 16) ^ ((row & 7) << 4)));
                    akk[m] = __builtin_amdgcn_mfma_f32_16x16x32_bf16(a, bw, akk[m], 0, 0, 0);
                }
            }
        }
        {
            const int col = 256 + wv * 16 + l15;
            for (int m = 0; m < 4; ++m) avv[m] = (f32x4){0.f, 0.f, 0.f, 0.f};
            for (int kk = 0; kk < 4; ++kk) {
                bf16x8 bw = *reinterpret_cast<const bf16x8*>(wqkvt + col * 128 + kk * 32 + l4 * 8);
                for (int m = 0; m < 4; ++m) {
                    int row = m * 16 + l15;
                    bf16x8 a = *reinterpret_cast<const bf16x8*>(
                        xb + row * 256 + ((kk * 64 + l4 * 16) ^ ((row & 7) << 4)));
                    avv[m] = __builtin_amdgcn_mfma_f32_16x16x32_bf16(a, bw, avv[m], 0, 0, 0);
                }
            }
        }
        __syncthreads();                                  // all xb reads done -> region1 reusable
        char* Ks = reg1;
        char* Vt = reg1 + 16384;
        float bk = qkv_b[128 + wv * 16 + l15];
        for (int m = 0; m < 4; ++m)
            for (int r = 0; r < 4; ++r) {
                int row = m * 16 + l4 * 4 + r;
                *reinterpret_cast<unsigned short*>(
                    Ks + h * 4096 + row * 64 + ((hc * 2) ^ ((row & 3) << 4)))
                    = f2bf(akk[m][r] + bk);
            }
        float bvv = qkv_b[256 + wv * 16 + l15];
        for (int m = 0; m < 4; ++m) {
            int tok0 = m * 16 + l4 * 4;                   // V transposed: [d=hc][tok]
            *reinterpret_cast<us4*>(
                Vt + h * 4096 + hc * 128 + ((tok0 * 2) ^ ((hc & 15) << 3)))
                = pack4(avv[m][0] + bvv, avv[m][1] + bvv, avv[m][2] + bvv, avv[m][3] + bvv);
        }
    }
    __syncthreads();

    // ---- Phase 2: attention (swapped S^T = K·Q^T; in-register softmax; PV 16x16x16) ----
    {
        const int h = wv >> 1, half = wv & 1;
        const char* Ks = reg1;
        const char* Vt = reg1 + 16384;
        const float* tp = tab + (size_t)(use_bm ? ((b & 63) * 4 + h) : h) * (49 * 64);
        const float* mp = mask + (size_t)(b & 63) * 2401;

        s4 pf[2][4];
        for (int m = 0; m < 2; ++m) {
            int tile = half * 2 + m;
            int qrow = tile * 16 + l15;
            bf16x8 qf = *reinterpret_cast<const bf16x8*>(
                reg0 + h * 4096 + qrow * 64 + ((l4 * 16) ^ ((qrow & 3) << 4)));
            f32x4 s[4];
            for (int n = 0; n < 4; ++n) {
                int row = n * 16 + l15;
                bf16x8 kf = *reinterpret_cast<const bf16x8*>(
                    Ks + h * 4096 + row * 64 + ((l4 * 16) ^ ((row & 3) << 4)));
                s[n] = __builtin_amdgcn_mfma_f32_16x16x32_bf16(kf, qf,
                        (f32x4){0.f, 0.f, 0.f, 0.f}, 0, 0, 0);
            }
            // lane (l15,l4) holds S[q = tile*16+l15][k = n*16 + l4*4 + r]
            bool qok = (tile < 3) || (l15 == 0);
            int qc = qok ? qrow : 48;
            const float* trow = tp + qc * 64 + l4 * 4;
            float vals[4][4];
            for (int n = 0; n < 4; ++n) {
                f32x4 t = *reinterpret_cast<const f32x4*>(trow + n * 16);
                for (int r = 0; r < 4; ++r) {
                    bool kok = (n < 3) || ((l4 | r) == 0);
                    float lv = -1e30f;
                    if (qok && kok) {
                        lv = s[n][r] + t[r];
                        if (!use_bm) lv += mp[qrow * 49 + n * 16 + l4 * 4 + r];
                    }
                    vals[n][r] = lv;
                }
            }
            float mx = -1e30f;
            for (int n = 0; n < 4; ++n)
                for (int r = 0; r < 4; ++r) mx = fmaxf(mx, vals[n][r]);
            mx = fmaxf(mx, __shfl_xor(mx, 16));
            mx = fmaxf(mx, __shfl_xor(mx, 32));
            float sum = 0.f;
            float p[4][4];
            for (int n = 0; n < 4; ++n)
                for (int r = 0; r < 4; ++r) { p[n][r] = __expf(vals[n][r] - mx); sum += p[n][r]; }
            sum += __shfl_xor(sum, 16);
            sum += __shfl_xor(sum, 32);
            float ri = __builtin_amdgcn_rcpf(sum);
            for (int n = 0; n < 4; ++n)
                pf[m][n] = __builtin_bit_cast(s4,
                    pack4(p[n][0] * ri, p[n][1] * ri, p[n][2] * ri, p[n][3] * ri));
        }
        // PV: X = P @ V via 16x16x16 (A = P in-register, B = V^T)
        f32x4 xacc[2][2];
        for (int m = 0; m < 2; ++m)
            for (int dt = 0; dt < 2; ++dt) xacc[m][dt] = (f32x4){0.f, 0.f, 0.f, 0.f};
        for (int n = 0; n < 4; ++n)
            for (int dt = 0; dt < 2; ++dt) {
                s4 vf = *reinterpret_cast<const s4*>(
                    Vt + h * 4096 + (dt * 16 + l15) * 128 + ((n * 32 + l4 * 8) ^ (l15 << 3)));
                for (int m = 0; m < 2; ++m)
                    xacc[m][dt] = __builtin_amdgcn_mfma_f32_16x16x16bf16_1k(pf[m][n], vf, xacc[m][dt], 0, 0, 0);
            }
        __syncthreads();           // all qf reads done -> region0 becomes X
        for (int m = 0; m < 2; ++m)
            for (int dt = 0; dt < 2; ++dt)
                for (int r = 0; r < 4; ++r) {
                    int row = (half * 2 + m) * 16 + l4 * 4 + r;
                    int col = h * 32 + dt * 16 + l15;
                    *reinterpret_cast<unsigned short*>(
                        reg0 + row * 256 + ((col * 2) ^ ((row & 7) << 4))) = f2bf(xacc[m][dt][r]);
                }
    }
    __syncthreads();

    // ---- Phase 3: out = X @ Wproj + b; stage f32 in LDS (swizzled), coalesced f32x4 store ----
    {
        const int col = wv * 16 + l15;
        f32x4 o[4];
        for (int m = 0; m < 4; ++m) o[m] = (f32x4){0.f, 0.f, 0.f, 0.f};
        for (int kk = 0; kk < 4; ++kk) {
            bf16x8 bw = *reinterpret_cast<const bf16x8*>(wprojt + col * 128 + kk * 32 + l4 * 8);
            for (int m = 0; m < 4; ++m) {
                int row = m * 16 + l15;
                bf16x8 a = *reinterpret_cast<const bf16x8*>(
                    reg0 + row * 256 + ((kk * 64 + l4 * 16) ^ ((row & 7) << 4)));
                o[m] = __builtin_amdgcn_mfma_f32_16x16x32_bf16(a, bw, o[m], 0, 0, 0);
            }
        }
        float pb = proj_b[col];
        char* outb = reg1;                                // [64][128] f32, swz ((row&7)<<4)
        for (int m = 0; m < 4; ++m)
            for (int r = 0; r < 4; ++r) {
                int row = m * 16 + l4 * 4 + r;
                *reinterpret_cast<float*>(
                    outb + row * 512 + ((col * 4) ^ ((row & 7) << 4))) = o[m][r] + pb;
            }
    }
    __syncthreads();
    {
        const char* outb = reg1;
        float* op = out + (size_t)b * 6272;
        for (int i = tid; i < 1568; i += 512) {
            int row = i >> 5;
            int cb  = (i & 31) * 16;
            f32x4 v = *reinterpret_cast<const f32x4*>(outb + row * 512 + (cb ^ ((row & 7) << 4)));
            *reinterpret_cast<f32x4*>(op + i * 4) = v;
        }
    }
}

extern "C" void kernel_launch(void* const* d_in, const int* in_sizes, int n_in,
                              void* d_out, int out_size, void* d_ws, size_t ws_size,
                              hipStream_t stream) {
    const float* x      = (const float*)d_in[0];
    const float* mask   = (const float*)d_in[1];
    const float* qkv_w  = (const float*)d_in[2];
    const float* qkv_b  = (const float*)d_in[3];
    const float* proj_w = (const float*)d_in[4];
    const float* proj_b = (const float*)d_in[5];
    const float* rpbt   = (const float*)d_in[6];
    float* out = (float*)d_out;

    unsigned short* wqkvt  = (unsigned short*)d_ws;                       // 98304 B
    unsigned short* wprojt = (unsigned short*)((char*)d_ws + 98304);      // 32768 B
    float*          tab    = (float*)((char*)d_ws + 131072);

    const size_t needed_big = 131072 + (size_t)64 * 4 * 49 * 64 * 4;      // ~3.34 MB
    int use_bm = (ws_size >= needed_big) ? 1 : 0;
    int total  = 65536 + (use_bm ? 64 * 4 * 49 * 64 : 4 * 49 * 64);

    wa_prep<<<(total + 255) / 256, 256, 0, stream>>>(qkv_w, proj_w, rpbt, mask, wqkvt, wprojt, tab, use_bm);
    wa_main<<<4096, 512, 0, stream>>>(x, mask, qkv_b, proj_b, wqkvt, wprojt, tab, use_bm, out);
}

// Round 5
// 127.874 us; speedup vs baseline: 1.7258x; 1.4829x over previous
//
#include <hip/hip_runtime.h>

typedef __bf16 bf16x8 __attribute__((ext_vector_type(8)));
typedef float f32x4 __attribute__((ext_vector_type(4)));
typedef unsigned short us4 __attribute__((ext_vector_type(4)));
typedef short s4 __attribute__((ext_vector_type(4)));

#define SCALE 0.17677669529663687f

__device__ __forceinline__ unsigned short f2bf(float f) {
    __bf16 h = (__bf16)f;                       // HW v_cvt (RNE)
    return __builtin_bit_cast(unsigned short, h);
}
__device__ __forceinline__ us4 pack4(float a, float b, float c, float d) {
    us4 r; r[0] = f2bf(a); r[1] = f2bf(b); r[2] = f2bf(c); r[3] = f2bf(d); return r;
}

// ---------------- prep: transpose+bf16 weights, build (bias[+mask]) table ----------------
__global__ void wa_prep(const float* __restrict__ qkv_w, const float* __restrict__ proj_w,
                        const float* __restrict__ rpbt, const float* __restrict__ mask,
                        unsigned short* __restrict__ wqkvt, unsigned short* __restrict__ wprojt,
                        float* __restrict__ tab, int use_bm) {
    int idx = blockIdx.x * 256 + threadIdx.x;
    if (idx < 49152) {                       // wqkvt[n][k] = qkv_w[k][n], bf16, (384,128)
        int n = idx >> 7, k = idx & 127;
        wqkvt[idx] = f2bf(qkv_w[k * 384 + n]);
    } else if (idx < 65536) {                // wprojt[n][k] = proj_w[k][n], bf16, (128,128)
        int j = idx - 49152;
        int n = j >> 7, k = j & 127;
        wprojt[j] = f2bf(proj_w[k * 128 + n]);
    } else {
        int j = idx - 65536;
        if (use_bm) {
            // BM[w][h][q][64] = bias + mask (k-stride 64)
            if (j < 64 * 4 * 49 * 64) {
                int k = j & 63; int t = j >> 6; int q = t % 49; t /= 49;
                int h = t & 3, w = t >> 2;
                float v = 0.f;
                if (k < 49) {
                    int rel = (q / 7 - k / 7 + 6) * 13 + (q % 7 - k % 7 + 6);
                    v = rpbt[rel * 4 + h] + mask[w * 2401 + q * 49 + k];
                }
                tab[j] = v;
            }
        } else {
            // biasP[h][q][64]
            if (j < 4 * 49 * 64) {
                int k = j & 63; int t = j >> 6; int q = t % 49; int h = t / 49;
                float v = 0.f;
                if (k < 49) {
                    int rel = (q / 7 - k / 7 + 6) * 13 + (q % 7 - k % 7 + 6);
                    v = rpbt[rel * 4 + h];
                }
                tab[j] = v;
            }
        }
    }
}

// ---------------- fused window attention: one block per window, 3 blocks/CU ----------------
// LDS (49152 B), non-aliased during phase 1 so only V is reg-held across a barrier:
//   Aq (    0..16384): Q [4][64][32] bf16 swz((row&3)<<4)  -> X [64][128] swz((row&7)<<4)
//   Bk (16384..32768): K [4][64][32] swz((row&3)<<4)
//   Cx (32768..49152): xb [64][128] swz((row&7)<<4) -> V [4][32][64] swz((d&15)<<3)
//   outb (16384..49152): f32 [64][128] swz((row&7)<<4), epilogue only (Bk,Cx dead)
// Register discipline: peak live ~60 unified regs (cap at 6 waves/EU is ~84).
__global__ __launch_bounds__(512, 6) void wa_main(
    const float* __restrict__ x, const float* __restrict__ mask,
    const float* __restrict__ qkv_b, const float* __restrict__ proj_b,
    const unsigned short* __restrict__ wqkvt, const unsigned short* __restrict__ wprojt,
    const float* __restrict__ tab, int use_bm, float* __restrict__ out)
{
    __shared__ __align__(16) char smem[49152];
    char* const Aq = smem;
    char* const Bk = smem + 16384;
    char* const Cx = smem + 32768;

    const int tid  = threadIdx.x;
    const int wv   = tid >> 6;
    const int lane = tid & 63;
    const int l15  = lane & 15;
    const int l4   = lane >> 4;
    const int b    = blockIdx.x;

    // ---- Phase 0: x (49x128 f32) -> xb bf16 (swizzled), zero-pad rows 49..63 ----
    {
        const float* xp = x + (size_t)b * 6272;
        for (int i = tid; i < 1568; i += 512) {          // 49*128/4
            int row = i >> 5;
            int cb  = (i & 31) * 8;
            f32x4 v = *reinterpret_cast<const f32x4*>(xp + i * 4);
            *reinterpret_cast<us4*>(Cx + row * 256 + (cb ^ ((row & 7) << 4))) =
                pack4(v[0], v[1], v[2], v[3]);
        }
        us4 z = (us4)(unsigned short)0;
        for (int i = tid; i < 480; i += 512) {           // 15 rows * 32 chunks
            int row = 49 + (i >> 5);
            int cb  = (i & 31) * 8;
            *reinterpret_cast<us4*>(Cx + row * 256 + (cb ^ ((row & 7) << 4))) = z;
        }
    }
    __syncthreads();

    // ---- Phase 1: qkv. Wave wv owns 16-col tile wv of each of Q, K, V (sequential) ----
    {
        const int h  = wv >> 1;
        const int hc = (wv & 1) * 16 + l15;

        // pass Q: store immediately to Aq
        {
            const int col = wv * 16 + l15;
            f32x4 acc[4];
            #pragma unroll
            for (int m = 0; m < 4; ++m) acc[m] = (f32x4){0.f, 0.f, 0.f, 0.f};
            #pragma unroll
            for (int kk = 0; kk < 4; ++kk) {
                bf16x8 bw = *reinterpret_cast<const bf16x8*>(wqkvt + col * 128 + kk * 32 + l4 * 8);
                #pragma unroll
                for (int m = 0; m < 4; ++m) {
                    int row = m * 16 + l15;
                    bf16x8 a = *reinterpret_cast<const bf16x8*>(
                        Cx + row * 256 + ((kk * 64 + l4 * 16) ^ ((row & 7) << 4)));
                    acc[m] = __builtin_amdgcn_mfma_f32_16x16x32_bf16(a, bw, acc[m], 0, 0, 0);
                }
            }
            float bq = qkv_b[col] * SCALE;
            #pragma unroll
            for (int m = 0; m < 4; ++m)
                #pragma unroll
                for (int r = 0; r < 4; ++r) {
                    int row = m * 16 + l4 * 4 + r;
                    *reinterpret_cast<unsigned short*>(
                        Aq + h * 4096 + row * 64 + ((hc * 2) ^ ((row & 3) << 4)))
                        = f2bf(acc[m][r] * SCALE + bq);
                }
        }
        // pass K: store immediately to Bk
        {
            const int col = 128 + wv * 16 + l15;
            f32x4 acc[4];
            #pragma unroll
            for (int m = 0; m < 4; ++m) acc[m] = (f32x4){0.f, 0.f, 0.f, 0.f};
            #pragma unroll
            for (int kk = 0; kk < 4; ++kk) {
                bf16x8 bw = *reinterpret_cast<const bf16x8*>(wqkvt + col * 128 + kk * 32 + l4 * 8);
                #pragma unroll
                for (int m = 0; m < 4; ++m) {
                    int row = m * 16 + l15;
                    bf16x8 a = *reinterpret_cast<const bf16x8*>(
                        Cx + row * 256 + ((kk * 64 + l4 * 16) ^ ((row & 7) << 4)));
                    acc[m] = __builtin_amdgcn_mfma_f32_16x16x32_bf16(a, bw, acc[m], 0, 0, 0);
                }
            }
            float bk = qkv_b[col];
            #pragma unroll
            for (int m = 0; m < 4; ++m)
                #pragma unroll
                for (int r = 0; r < 4; ++r) {
                    int row = m * 16 + l4 * 4 + r;
                    *reinterpret_cast<unsigned short*>(
                        Bk + h * 4096 + row * 64 + ((hc * 2) ^ ((row & 3) << 4)))
                        = f2bf(acc[m][r] + bk);
                }
        }
        // pass V: hold across the xb->V alias barrier (16 regs)
        f32x4 avv[4];
        #pragma unroll
        for (int m = 0; m < 4; ++m) avv[m] = (f32x4){0.f, 0.f, 0.f, 0.f};
        {
            const int col = 256 + wv * 16 + l15;
            #pragma unroll
            for (int kk = 0; kk < 4; ++kk) {
                bf16x8 bw = *reinterpret_cast<const bf16x8*>(wqkvt + col * 128 + kk * 32 + l4 * 8);
                #pragma unroll
                for (int m = 0; m < 4; ++m) {
                    int row = m * 16 + l15;
                    bf16x8 a = *reinterpret_cast<const bf16x8*>(
                        Cx + row * 256 + ((kk * 64 + l4 * 16) ^ ((row & 7) << 4)));
                    avv[m] = __builtin_amdgcn_mfma_f32_16x16x32_bf16(a, bw, avv[m], 0, 0, 0);
                }
            }
        }
        __syncthreads();                                  // all xb reads done -> Cx reusable
        float bvv = qkv_b[256 + wv * 16 + l15];
        #pragma unroll
        for (int m = 0; m < 4; ++m) {
            int tok0 = m * 16 + l4 * 4;                   // V transposed: [d=hc][tok]
            *reinterpret_cast<us4*>(
                Cx + h * 4096 + hc * 128 + ((tok0 * 2) ^ ((hc & 15) << 3)))
                = pack4(avv[m][0] + bvv, avv[m][1] + bvv, avv[m][2] + bvv, avv[m][3] + bvv);
        }
    }
    __syncthreads();

    // ---- Phase 2: attention. Sequential m-tiles, streaming in-place softmax ----
    {
        const int h = wv >> 1, half = wv & 1;
        const float* tp = tab + (size_t)(use_bm ? ((b & 63) * 4 + h) : h) * (49 * 64);
        const float* mp = mask + (size_t)(b & 63) * 2401;

        f32x4 xacc[2][2];
        #pragma unroll
        for (int m = 0; m < 2; ++m)
            #pragma unroll
            for (int dt = 0; dt < 2; ++dt) xacc[m][dt] = (f32x4){0.f, 0.f, 0.f, 0.f};

        #pragma unroll
        for (int m = 0; m < 2; ++m) {
            const int tile = half * 2 + m;
            const int qrow = tile * 16 + l15;
            bf16x8 qf = *reinterpret_cast<const bf16x8*>(
                Aq + h * 4096 + qrow * 64 + ((l4 * 16) ^ ((qrow & 3) << 4)));
            f32x4 sv[4];
            #pragma unroll
            for (int n = 0; n < 4; ++n) {
                int row = n * 16 + l15;
                bf16x8 kf = *reinterpret_cast<const bf16x8*>(
                    Bk + h * 4096 + row * 64 + ((l4 * 16) ^ ((row & 3) << 4)));
                sv[n] = __builtin_amdgcn_mfma_f32_16x16x32_bf16(kf, qf,
                        (f32x4){0.f, 0.f, 0.f, 0.f}, 0, 0, 0);
            }
            // lane (l15,l4) holds S[q=qrow][k = n*16 + l4*4 + r]
            const bool qok = (tile < 3) || (l15 == 0);
            const int qc = qok ? qrow : 48;
            const float* trow = tp + qc * 64 + l4 * 4;
            float mx = -1e30f;
            #pragma unroll
            for (int n = 0; n < 4; ++n) {
                f32x4 t = *reinterpret_cast<const f32x4*>(trow + n * 16);
                #pragma unroll
                for (int r = 0; r < 4; ++r) {
                    bool kok = (n < 3) || ((l4 | r) == 0);
                    float lv = sv[n][r] + t[r];
                    if (!use_bm && qok && kok) lv += mp[qrow * 49 + n * 16 + l4 * 4 + r];
                    lv = (qok && kok) ? lv : -1e30f;
                    sv[n][r] = lv;
                    mx = fmaxf(mx, lv);
                }
            }
            mx = fmaxf(mx, __shfl_xor(mx, 16));
            mx = fmaxf(mx, __shfl_xor(mx, 32));
            float sum = 0.f;
            #pragma unroll
            for (int n = 0; n < 4; ++n)
                #pragma unroll
                for (int r = 0; r < 4; ++r) {
                    float e = __expf(sv[n][r] - mx);
                    sv[n][r] = e;
                    sum += e;
                }
            sum += __shfl_xor(sum, 16);
            sum += __shfl_xor(sum, 32);
            float ri = __builtin_amdgcn_rcpf(sum);
            // pack + PV immediately (pf transient, 1 reg at a time)
            #pragma unroll
            for (int n = 0; n < 4; ++n) {
                s4 pfn = __builtin_bit_cast(s4,
                    pack4(sv[n][0] * ri, sv[n][1] * ri, sv[n][2] * ri, sv[n][3] * ri));
                #pragma unroll
                for (int dt = 0; dt < 2; ++dt) {
                    s4 vf = *reinterpret_cast<const s4*>(
                        Cx + h * 4096 + (dt * 16 + l15) * 128 + ((n * 32 + l4 * 8) ^ (l15 << 3)));
                    xacc[m][dt] = __builtin_amdgcn_mfma_f32_16x16x16bf16_1k(pfn, vf, xacc[m][dt], 0, 0, 0);
                }
            }
        }
        __syncthreads();           // all Aq (Q) reads done -> Aq becomes X
        #pragma unroll
        for (int m = 0; m < 2; ++m)
            #pragma unroll
            for (int dt = 0; dt < 2; ++dt)
                #pragma unroll
                for (int r = 0; r < 4; ++r) {
                    int row = (half * 2 + m) * 16 + l4 * 4 + r;
                    int col = h * 32 + dt * 16 + l15;
                    *reinterpret_cast<unsigned short*>(
                        Aq + row * 256 + ((col * 2) ^ ((row & 7) << 4))) = f2bf(xacc[m][dt][r]);
                }
    }
    __syncthreads();

    // ---- Phase 3: out = X @ Wproj + b; stage f32 in LDS (Bk/Cx dead), coalesced store ----
    {
        const int col = wv * 16 + l15;
        f32x4 o[4];
        #pragma unroll
        for (int m = 0; m < 4; ++m) o[m] = (f32x4){0.f, 0.f, 0.f, 0.f};
        #pragma unroll
        for (int kk = 0; kk < 4; ++kk) {
            bf16x8 bw = *reinterpret_cast<const bf16x8*>(wprojt + col * 128 + kk * 32 + l4 * 8);
            #pragma unroll
            for (int m = 0; m < 4; ++m) {
                int row = m * 16 + l15;
                bf16x8 a = *reinterpret_cast<const bf16x8*>(
                    Aq + row * 256 + ((kk * 64 + l4 * 16) ^ ((row & 7) << 4)));
                o[m] = __builtin_amdgcn_mfma_f32_16x16x32_bf16(a, bw, o[m], 0, 0, 0);
            }
        }
        float pb = proj_b[col];
        char* outb = Bk;                                  // [64][128] f32, swz ((row&7)<<4)
        #pragma unroll
        for (int m = 0; m < 4; ++m)
            #pragma unroll
            for (int r = 0; r < 4; ++r) {
                int row = m * 16 + l4 * 4 + r;
                *reinterpret_cast<float*>(
                    outb + row * 512 + ((col * 4) ^ ((row & 7) << 4))) = o[m][r] + pb;
            }
    }
    __syncthreads();
    {
        const char* outb = Bk;
        float* op = out + (size_t)b * 6272;
        for (int i = tid; i < 1568; i += 512) {
            int row = i >> 5;
            int cb  = (i & 31) * 16;
            f32x4 v = *reinterpret_cast<const f32x4*>(outb + row * 512 + (cb ^ ((row & 7) << 4)));
            *reinterpret_cast<f32x4*>(op + i * 4) = v;
        }
    }
}

extern "C" void kernel_launch(void* const* d_in, const int* in_sizes, int n_in,
                              void* d_out, int out_size, void* d_ws, size_t ws_size,
                              hipStream_t stream) {
    const float* x      = (const float*)d_in[0];
    const float* mask   = (const float*)d_in[1];
    const float* qkv_w  = (const float*)d_in[2];
    const float* qkv_b  = (const float*)d_in[3];
    const float* proj_w = (const float*)d_in[4];
    const float* proj_b = (const float*)d_in[5];
    const float* rpbt   = (const float*)d_in[6];
    float* out = (float*)d_out;

    unsigned short* wqkvt  = (unsigned short*)d_ws;                       // 98304 B
    unsigned short* wprojt = (unsigned short*)((char*)d_ws + 98304);      // 32768 B
    float*          tab    = (float*)((char*)d_ws + 131072);

    const size_t needed_big = 131072 + (size_t)64 * 4 * 49 * 64 * 4;      // ~3.34 MB
    int use_bm = (ws_size >= needed_big) ? 1 : 0;
    int total  = 65536 + (use_bm ? 64 * 4 * 49 * 64 : 4 * 49 * 64);

    wa_prep<<<(total + 255) / 256, 256, 0, stream>>>(qkv_w, proj_w, rpbt, mask, wqkvt, wprojt, tab, use_bm);
    wa_main<<<4096, 512, 0, stream>>>(x, mask, qkv_b, proj_b, wqkvt, wprojt, tab, use_bm, out);
}